// Round 1
// baseline (338.286 us; speedup 1.0000x reference)
//
#include <hip/hip_runtime.h>
#include <hip/hip_bf16.h>
#include <stdint.h>

// Problem constants (from reference): N=4096, K=2, E=8, D=1024, H=1024
#define N_TOK   4096
#define TOPK    2
#define N_EXP   8
#define D_MODEL 1024
#define H_DIM   1024
#define NK      (N_TOK * TOPK)   // 8192 token-copies
#define MAX_TILES 72             // max sum over experts of ceil(gs/128) = 64 + 7

typedef __attribute__((ext_vector_type(8))) short bf16x8;  // 8 bf16 in 4 VGPRs
typedef __attribute__((ext_vector_type(4))) float f32x4;   // MFMA accumulator
typedef unsigned short bfbits;

__device__ inline bfbits f2bf_bits(float f) {
  union { float f; unsigned int u; } v; v.f = f;
  unsigned int r = v.u + 0x7FFFu + ((v.u >> 16) & 1u);  // RNE
  return (bfbits)(r >> 16);
}

// meta layout (ints): [0..8] offs (exclusive scan, offs[8]=8192), [9..16] cnt,
//                     [17] ntiles, [18..89] tile_expert, [90..161] tile_row0
__global__ void prep_kernel(const int* __restrict__ bspe, int* __restrict__ meta) {
  if (threadIdx.x == 0) {
    int acc = 0, nt = 0;
    for (int e = 0; e < N_EXP; e++) {
      meta[e] = acc;
      meta[9 + e] = 0;
      int g = bspe[e];
      for (int t = 0; t * 128 < g; t++) {
        meta[18 + nt] = e;
        meta[90 + nt] = acc + t * 128;
        nt++;
      }
      acc += g;
    }
    meta[8] = acc;
    meta[17] = nt;
  }
}

__global__ void bucket_kernel(const int* __restrict__ eidx, int* __restrict__ meta,
                              int* __restrict__ row_src) {
  int i = blockIdx.x * 256 + threadIdx.x;
  if (i < NK) {
    int e = eidx[i];
    int p = meta[e] + atomicAdd(&meta[9 + e], 1);  // order within expert irrelevant
    row_src[p] = i;
  }
}

__global__ void convx_kernel(const float4* __restrict__ x, ushort4* __restrict__ xb) {
  int i = blockIdx.x * 256 + threadIdx.x;  // one float4 -> 4 bf16
  float4 v = x[i];
  ushort4 o;
  o.x = f2bf_bits(v.x); o.y = f2bf_bits(v.y);
  o.z = f2bf_bits(v.z); o.w = f2bf_bits(v.w);
  xb[i] = o;
}

// Transpose+convert all 24 1024x1024 weight matrices:
//   w1 (E,D,H) -> w1t (E,H,D) bf16 ; w3 likewise ; w2 (E,H,D) -> w2t (E,D,H) bf16
// so that every GEMM "B" operand is k-contiguous.
__global__ void wtrans_kernel(const float* __restrict__ w1, const float* __restrict__ w2,
                              const float* __restrict__ w3,
                              bfbits* __restrict__ w1t, bfbits* __restrict__ w2t,
                              bfbits* __restrict__ w3t) {
  int z = blockIdx.z;
  const size_t MAT = (size_t)1024 * 1024;
  const float* src; bfbits* dst;
  if (z < 8)       { src = w1 + (size_t)z * MAT;        dst = w1t + (size_t)z * MAT; }
  else if (z < 16) { src = w3 + (size_t)(z - 8) * MAT;  dst = w3t + (size_t)(z - 8) * MAT; }
  else             { src = w2 + (size_t)(z - 16) * MAT; dst = w2t + (size_t)(z - 16) * MAT; }
  __shared__ bfbits tl[64][72];  // +8 pad breaks bank aliasing on transposed read
  int tx = threadIdx.x & 63, ty = threadIdx.x >> 6;
  int r0 = blockIdx.y * 64, c0 = blockIdx.x * 64;
  for (int it = 0; it < 16; it++) {
    int r = ty + it * 4;
    tl[r][tx] = f2bf_bits(src[(size_t)(r0 + r) * 1024 + c0 + tx]);
  }
  __syncthreads();
  for (int it = 0; it < 16; it++) {
    int r = ty + it * 4;
    dst[(size_t)(c0 + r) * 1024 + r0 + tx] = tl[tx][r];
  }
}

// ---- grouped GEMM 1: h = silu(x_perm @ w1) * (x_perm @ w3), output bf16 (NK,H) ----
// Tile: 128 rows x 128 cols x BK=32. 4 waves, each 64x64 (4x4 MFMA subtiles, dual acc).
__global__ __launch_bounds__(256, 2) void gemm_swiglu_kernel(
    const bfbits* __restrict__ xb, const bfbits* __restrict__ w1t,
    const bfbits* __restrict__ w3t, const int* __restrict__ row_src,
    const int* __restrict__ meta, bfbits* __restrict__ hb) {
  int nt = meta[17];
  int bt = blockIdx.x;
  if (bt >= nt) return;
  int e = meta[18 + bt];
  int row0 = meta[90 + bt];
  int rows_end = meta[e + 1];
  int n0 = blockIdx.y * 128;

  __shared__ __align__(16) bfbits As[128 * 32];
  __shared__ __align__(16) bfbits B1s[128 * 32];
  __shared__ __align__(16) bfbits B3s[128 * 32];

  int tid = threadIdx.x;
  int lane = tid & 63, wv = tid >> 6;
  int r1 = tid >> 2, r2 = r1 + 64, seg = tid & 3;  // 512 16B-chunks per tile, 2/thread

  int gr1 = row0 + r1, gr2 = row0 + r2;
  int tok1 = (gr1 < rows_end) ? (row_src[gr1] >> 1) : (row_src[row0] >> 1);
  int tok2 = (gr2 < rows_end) ? (row_src[gr2] >> 1) : (row_src[row0] >> 1);

  const bfbits* aP1 = xb + (size_t)tok1 * D_MODEL + seg * 8;
  const bfbits* aP2 = xb + (size_t)tok2 * D_MODEL + seg * 8;
  const bfbits* b1P1 = w1t + ((size_t)e * H_DIM + n0 + r1) * D_MODEL + seg * 8;
  const bfbits* b1P2 = w1t + ((size_t)e * H_DIM + n0 + r2) * D_MODEL + seg * 8;
  const bfbits* b3P1 = w3t + ((size_t)e * H_DIM + n0 + r1) * D_MODEL + seg * 8;
  const bfbits* b3P2 = w3t + ((size_t)e * H_DIM + n0 + r2) * D_MODEL + seg * 8;

  const f32x4 fzero = {0.f, 0.f, 0.f, 0.f};
  f32x4 accg[4][4], accu[4][4];
  for (int i = 0; i < 4; i++)
    for (int j = 0; j < 4; j++) { accg[i][j] = fzero; accu[i][j] = fzero; }

  int mw = (wv & 1) * 64, nw = (wv >> 1) * 64;
  int qd = lane >> 4, lr = lane & 15;

  for (int kk = 0; kk < D_MODEL / 32; kk++) {
    int k0 = kk * 32;
    bf16x8 va1 = *(const bf16x8*)(aP1 + k0);
    bf16x8 va2 = *(const bf16x8*)(aP2 + k0);
    bf16x8 vb11 = *(const bf16x8*)(b1P1 + k0);
    bf16x8 vb12 = *(const bf16x8*)(b1P2 + k0);
    bf16x8 vb31 = *(const bf16x8*)(b3P1 + k0);
    bf16x8 vb32 = *(const bf16x8*)(b3P2 + k0);
    __syncthreads();  // prev iter's LDS reads done
    *(bf16x8*)&As[r1 * 32 + seg * 8] = va1;
    *(bf16x8*)&As[r2 * 32 + seg * 8] = va2;
    *(bf16x8*)&B1s[r1 * 32 + seg * 8] = vb11;
    *(bf16x8*)&B1s[r2 * 32 + seg * 8] = vb12;
    *(bf16x8*)&B3s[r1 * 32 + seg * 8] = vb31;
    *(bf16x8*)&B3s[r2 * 32 + seg * 8] = vb32;
    __syncthreads();
    bf16x8 af[4], b1f[4], b3f[4];
    for (int mi = 0; mi < 4; mi++)
      af[mi] = *(const bf16x8*)&As[(mw + mi * 16 + lr) * 32 + qd * 8];
    for (int ni = 0; ni < 4; ni++) {
      b1f[ni] = *(const bf16x8*)&B1s[(nw + ni * 16 + lr) * 32 + qd * 8];
      b3f[ni] = *(const bf16x8*)&B3s[(nw + ni * 16 + lr) * 32 + qd * 8];
    }
    for (int mi = 0; mi < 4; mi++)
      for (int ni = 0; ni < 4; ni++) {
        accg[mi][ni] = __builtin_amdgcn_mfma_f32_16x16x32_bf16(af[mi], b1f[ni], accg[mi][ni], 0, 0, 0);
        accu[mi][ni] = __builtin_amdgcn_mfma_f32_16x16x32_bf16(af[mi], b3f[ni], accu[mi][ni], 0, 0, 0);
      }
  }

  // epilogue: C/D layout row=(lane>>4)*4+reg, col=lane&15 (verified m89/m91)
  for (int mi = 0; mi < 4; mi++) {
    int rbase = row0 + mw + mi * 16 + qd * 4;
    for (int r = 0; r < 4; r++) {
      int grow = rbase + r;
      if (grow < rows_end) {
        for (int ni = 0; ni < 4; ni++) {
          float g = accg[mi][ni][r], u = accu[mi][ni][r];
          float h = g / (1.f + __expf(-g)) * u;  // silu(g)*u
          hb[(size_t)grow * H_DIM + n0 + nw + ni * 16 + lr] = f2bf_bits(h);
        }
      }
    }
  }
}

// ---- grouped GEMM 2: out_perm = h @ w2 ; weighted atomic scatter into out ----
__global__ __launch_bounds__(256, 2) void gemm_out_kernel(
    const bfbits* __restrict__ hb, const bfbits* __restrict__ w2t,
    const int* __restrict__ row_src, const int* __restrict__ meta,
    const float* __restrict__ ew, float* __restrict__ out) {
  int nt = meta[17];
  int bt = blockIdx.x;
  if (bt >= nt) return;
  int e = meta[18 + bt];
  int row0 = meta[90 + bt];
  int rows_end = meta[e + 1];
  int n0 = blockIdx.y * 128;

  __shared__ __align__(16) bfbits As[128 * 32];
  __shared__ __align__(16) bfbits Bs[128 * 32];

  int tid = threadIdx.x;
  int lane = tid & 63, wv = tid >> 6;
  int r1 = tid >> 2, r2 = r1 + 64, seg = tid & 3;
  int gr1 = row0 + r1, gr2 = row0 + r2;
  int sr1 = (gr1 < rows_end) ? gr1 : row0;
  int sr2 = (gr2 < rows_end) ? gr2 : row0;
  const bfbits* aP1 = hb + (size_t)sr1 * H_DIM + seg * 8;
  const bfbits* aP2 = hb + (size_t)sr2 * H_DIM + seg * 8;
  const bfbits* bP1 = w2t + ((size_t)e * D_MODEL + n0 + r1) * H_DIM + seg * 8;
  const bfbits* bP2 = w2t + ((size_t)e * D_MODEL + n0 + r2) * H_DIM + seg * 8;

  const f32x4 fzero = {0.f, 0.f, 0.f, 0.f};
  f32x4 acc[4][4];
  for (int i = 0; i < 4; i++)
    for (int j = 0; j < 4; j++) acc[i][j] = fzero;

  int mw = (wv & 1) * 64, nw = (wv >> 1) * 64;
  int qd = lane >> 4, lr = lane & 15;

  for (int kk = 0; kk < H_DIM / 32; kk++) {
    int k0 = kk * 32;
    bf16x8 va1 = *(const bf16x8*)(aP1 + k0);
    bf16x8 va2 = *(const bf16x8*)(aP2 + k0);
    bf16x8 vb1 = *(const bf16x8*)(bP1 + k0);
    bf16x8 vb2 = *(const bf16x8*)(bP2 + k0);
    __syncthreads();
    *(bf16x8*)&As[r1 * 32 + seg * 8] = va1;
    *(bf16x8*)&As[r2 * 32 + seg * 8] = va2;
    *(bf16x8*)&Bs[r1 * 32 + seg * 8] = vb1;
    *(bf16x8*)&Bs[r2 * 32 + seg * 8] = vb2;
    __syncthreads();
    bf16x8 af[4], bf[4];
    for (int mi = 0; mi < 4; mi++)
      af[mi] = *(const bf16x8*)&As[(mw + mi * 16 + lr) * 32 + qd * 8];
    for (int ni = 0; ni < 4; ni++)
      bf[ni] = *(const bf16x8*)&Bs[(nw + ni * 16 + lr) * 32 + qd * 8];
    for (int mi = 0; mi < 4; mi++)
      for (int ni = 0; ni < 4; ni++)
        acc[mi][ni] = __builtin_amdgcn_mfma_f32_16x16x32_bf16(af[mi], bf[ni], acc[mi][ni], 0, 0, 0);
  }

  for (int mi = 0; mi < 4; mi++) {
    int rbase = row0 + mw + mi * 16 + qd * 4;
    for (int r = 0; r < 4; r++) {
      int grow = rbase + r;
      if (grow < rows_end) {
        int ci = row_src[grow];          // copy index in [0, NK)
        int tok = ci >> 1;               // TOPK = 2
        float w = ew[ci];
        for (int ni = 0; ni < 4; ni++) {
          atomicAdd(&out[(size_t)tok * D_MODEL + n0 + nw + ni * 16 + lr],
                    w * acc[mi][ni][r]);
        }
      }
    }
  }
}

extern "C" void kernel_launch(void* const* d_in, const int* in_sizes, int n_in,
                              void* d_out, int out_size, void* d_ws, size_t ws_size,
                              hipStream_t stream) {
  const float* x  = (const float*)d_in[0];
  const float* ew = (const float*)d_in[1];
  const int* eidx = (const int*)d_in[2];
  const int* bspe = (const int*)d_in[3];
  const float* w1 = (const float*)d_in[4];
  const float* w2 = (const float*)d_in[5];
  const float* w3 = (const float*)d_in[6];
  float* out = (float*)d_out;

  char* ws = (char*)d_ws;
  const size_t MB = 1024 * 1024;
  bfbits* w1t   = (bfbits*)(ws);             // 16 MB (E,H,D)
  bfbits* w3t   = (bfbits*)(ws + 16 * MB);   // 16 MB (E,H,D)
  bfbits* w2t   = (bfbits*)(ws + 32 * MB);   // 16 MB (E,D,H)
  bfbits* xb    = (bfbits*)(ws + 48 * MB);   //  8 MB (N,D)
  bfbits* hb    = (bfbits*)(ws + 56 * MB);   // 16 MB (NK,H)
  int* row_src  = (int*)(ws + 72 * MB);      // 32 KB
  int* meta     = (int*)(ws + 72 * MB + 64 * 1024);

  hipMemsetAsync(d_out, 0, (size_t)out_size * sizeof(float), stream);
  prep_kernel<<<1, 64, 0, stream>>>(bspe, meta);
  bucket_kernel<<<NK / 256, 256, 0, stream>>>(eidx, meta, row_src);
  convx_kernel<<<(N_TOK * D_MODEL / 4) / 256, 256, 0, stream>>>((const float4*)x, (ushort4*)xb);
  wtrans_kernel<<<dim3(16, 16, 24), 256, 0, stream>>>(w1, w2, w3, w1t, w2t, w3t);
  gemm_swiglu_kernel<<<dim3(MAX_TILES, H_DIM / 128), 256, 0, stream>>>(
      xb, w1t, w3t, row_src, meta, hb);
  gemm_out_kernel<<<dim3(MAX_TILES, D_MODEL / 128), 256, 0, stream>>>(
      hb, w2t, row_src, meta, ew, out);
}

// Round 2
// 305.394 us; speedup vs baseline: 1.1077x; 1.1077x over previous
//
#include <hip/hip_runtime.h>
#include <hip/hip_bf16.h>
#include <stdint.h>

// Problem constants: N=4096, K=2, E=8, D=1024, H=1024
#define N_TOK   4096
#define TOPK    2
#define N_EXP   8
#define D_MODEL 1024
#define H_DIM   1024
#define NK      (N_TOK * TOPK)   // 8192 token-copies
#define MAX_TILES 72             // sum over experts of ceil(gs/128) <= 64+7

typedef __attribute__((ext_vector_type(8))) short bf16x8;  // 8 bf16 (4 VGPRs)
typedef __attribute__((ext_vector_type(4))) float f32x4;   // MFMA accumulator
typedef unsigned short bfbits;

__device__ inline bfbits f2bf_bits(float f) {
  union { float f; unsigned int u; } v; v.f = f;
  unsigned int r = v.u + 0x7FFFu + ((v.u >> 16) & 1u);  // RNE
  return (bfbits)(r >> 16);
}

// async global->LDS, 16B per lane; LDS dest is wave-uniform base + lane*16
__device__ inline void glds16(const bfbits* g, bfbits* l) {
  __builtin_amdgcn_global_load_lds(
      (const __attribute__((address_space(1))) void*)g,
      (__attribute__((address_space(3))) void*)l, 16, 0, 0);
}

// meta: [0..8] offs (excl scan), [9..16] cnt, [17] ntiles,
//       [18..89] tile_expert, [90..161] tile_row0
__global__ void prep_kernel(const int* __restrict__ bspe, int* __restrict__ meta) {
  if (threadIdx.x == 0) {
    int acc = 0, nt = 0;
    for (int e = 0; e < N_EXP; e++) {
      meta[e] = acc;
      meta[9 + e] = 0;
      int g = bspe[e];
      for (int t = 0; t * 128 < g; t++) {
        meta[18 + nt] = e;
        meta[90 + nt] = acc + t * 128;
        nt++;
      }
      acc += g;
    }
    meta[8] = acc;
    meta[17] = nt;
  }
}

__global__ void bucket_kernel(const int* __restrict__ eidx, int* __restrict__ meta,
                              int* __restrict__ row_src, int* __restrict__ pos_of) {
  int i = blockIdx.x * 256 + threadIdx.x;
  if (i < NK) {
    int e = eidx[i];
    int p = meta[e] + atomicAdd(&meta[9 + e], 1);
    row_src[p] = i;
    pos_of[i] = p;   // inverse permutation for the combine pass
  }
}

__global__ void convx_kernel(const float4* __restrict__ x, ushort4* __restrict__ xb) {
  int i = blockIdx.x * 256 + threadIdx.x;
  float4 v = x[i];
  ushort4 o;
  o.x = f2bf_bits(v.x); o.y = f2bf_bits(v.y);
  o.z = f2bf_bits(v.z); o.w = f2bf_bits(v.w);
  xb[i] = o;
}

// Transpose+convert 24 1024x1024 fp32 matrices -> bf16 transposed.
// LDS pad 65 (odd stride -> 2-way banks, free); transposed stores as ushort4.
__global__ void wtrans_kernel(const float* __restrict__ w1, const float* __restrict__ w2,
                              const float* __restrict__ w3,
                              bfbits* __restrict__ w1t, bfbits* __restrict__ w2t,
                              bfbits* __restrict__ w3t) {
  int z = blockIdx.z;
  const size_t MAT = (size_t)1024 * 1024;
  const float* src; bfbits* dst;
  if (z < 8)       { src = w1 + (size_t)z * MAT;        dst = w1t + (size_t)z * MAT; }
  else if (z < 16) { src = w3 + (size_t)(z - 8) * MAT;  dst = w3t + (size_t)(z - 8) * MAT; }
  else             { src = w2 + (size_t)(z - 16) * MAT; dst = w2t + (size_t)(z - 16) * MAT; }
  __shared__ bfbits tl[64][65];
  int tid = threadIdx.x;
  int tx = tid & 63, ty = tid >> 6;
  int r0 = blockIdx.y * 64, c0 = blockIdx.x * 64;
  for (int it = 0; it < 16; it++) {
    int r = ty + it * 4;
    tl[r][tx] = f2bf_bits(src[(size_t)(r0 + r) * 1024 + c0 + tx]);
  }
  __syncthreads();
  for (int it = 0; it < 4; it++) {
    int o = (tid >> 4) + it * 16;   // output row (= source col) 0..63
    int r4 = (tid & 15) * 4;        // source-row quad
    ushort4 v;
    v.x = tl[r4 + 0][o]; v.y = tl[r4 + 1][o];
    v.z = tl[r4 + 2][o]; v.w = tl[r4 + 3][o];
    *(ushort4*)&dst[(size_t)(c0 + o) * 1024 + r0 + r4] = v;
  }
}

// ---- grouped GEMM 1: h = silu(x@w1) * (x@w3), bf16 out (NK,H) ----
// m97 structure: glds width-16 staging, 2-barrier K-loop, 128x128xBK32 tile.
// XOR segment swizzle: store lane fetches global seg g = (lane&3)^((lane>>3)&3)
// -> LDS slot (row, lane&3); read slot for (row,qd) is qd^((lr>>1)&3). 2-way banks.
__global__ __launch_bounds__(256, 2) void gemm_swiglu_kernel(
    const bfbits* __restrict__ xb, const bfbits* __restrict__ w1t,
    const bfbits* __restrict__ w3t, const int* __restrict__ row_src,
    const int* __restrict__ meta, bfbits* __restrict__ hb) {
  int nt = meta[17];
  int bt = blockIdx.y;
  if (bt >= nt) return;
  int e = meta[18 + bt];
  int row0 = meta[90 + bt];
  int rows_end = meta[e + 1];
  int n0 = blockIdx.x * 128;

  __shared__ __align__(16) bfbits As[128 * 32];
  __shared__ __align__(16) bfbits B1s[128 * 32];
  __shared__ __align__(16) bfbits B3s[128 * 32];

  int tid = threadIdx.x, lane = tid & 63, wv = tid >> 6;
  int g = (lane & 3) ^ ((lane >> 3) & 3);  // swizzled global 16B segment
  int rlo = lane >> 2;                      // row within a 16-row glds call

  const bfbits* apt[2]; const bfbits* b1pt[2]; const bfbits* b3pt[2];
  int ldsoff[2];
  for (int j = 0; j < 2; j++) {
    int s = 2 * wv + j;
    int rit = 16 * s + rlo;
    int gr = row0 + rit;
    int tok = row_src[(gr < rows_end) ? gr : row0] >> 1;  // TOPK=2
    apt[j]  = xb  + (size_t)tok * D_MODEL + g * 8;
    b1pt[j] = w1t + ((size_t)e * H_DIM + n0 + rit) * D_MODEL + g * 8;
    b3pt[j] = w3t + ((size_t)e * H_DIM + n0 + rit) * D_MODEL + g * 8;
    ldsoff[j] = s * 512;
  }

  const f32x4 fzero = {0.f, 0.f, 0.f, 0.f};
  f32x4 accg[4][4], accu[4][4];
  for (int i = 0; i < 4; i++)
    for (int j = 0; j < 4; j++) { accg[i][j] = fzero; accu[i][j] = fzero; }

  int mw = (wv & 1) * 64, nw = (wv >> 1) * 64;
  int qd = lane >> 4, lr = lane & 15;
  int slot = (qd ^ ((lr >> 1) & 3)) << 3;  // element offset of my 16B slot

  for (int kk = 0; kk < D_MODEL / 32; kk++) {
    int ko = kk * 32;
    glds16(apt[0] + ko, As + ldsoff[0]);
    glds16(apt[1] + ko, As + ldsoff[1]);
    glds16(b1pt[0] + ko, B1s + ldsoff[0]);
    glds16(b1pt[1] + ko, B1s + ldsoff[1]);
    glds16(b3pt[0] + ko, B3s + ldsoff[0]);
    glds16(b3pt[1] + ko, B3s + ldsoff[1]);
    __syncthreads();  // vmcnt(0) drain + all waves staged
    bf16x8 af[4], b1f[4], b3f[4];
    for (int mi = 0; mi < 4; mi++)
      af[mi] = *(const bf16x8*)&As[(mw + mi * 16 + lr) * 32 + slot];
    for (int ni = 0; ni < 4; ni++) {
      b1f[ni] = *(const bf16x8*)&B1s[(nw + ni * 16 + lr) * 32 + slot];
      b3f[ni] = *(const bf16x8*)&B3s[(nw + ni * 16 + lr) * 32 + slot];
    }
    for (int mi = 0; mi < 4; mi++)
      for (int ni = 0; ni < 4; ni++) {
        accg[mi][ni] = __builtin_amdgcn_mfma_f32_16x16x32_bf16(af[mi], b1f[ni], accg[mi][ni], 0, 0, 0);
        accu[mi][ni] = __builtin_amdgcn_mfma_f32_16x16x32_bf16(af[mi], b3f[ni], accu[mi][ni], 0, 0, 0);
      }
    __syncthreads();  // all reads done before next overwrite
  }

  // C/D layout: row=(lane>>4)*4+reg, col=lane&15
  for (int mi = 0; mi < 4; mi++) {
    int rbase = row0 + mw + mi * 16 + qd * 4;
    for (int r = 0; r < 4; r++) {
      int grow = rbase + r;
      if (grow < rows_end) {
        for (int ni = 0; ni < 4; ni++) {
          float gg = accg[mi][ni][r], u = accu[mi][ni][r];
          float h = gg / (1.f + __expf(-gg)) * u;  // silu(g)*u
          hb[(size_t)grow * H_DIM + n0 + nw + ni * 16 + lr] = f2bf_bits(h);
        }
      }
    }
  }
}

// ---- grouped GEMM 2: out_perm = h @ w2 (fp32, no atomics) ----
__global__ __launch_bounds__(256, 2) void gemm_out_kernel(
    const bfbits* __restrict__ hb, const bfbits* __restrict__ w2t,
    const int* __restrict__ meta, float* __restrict__ out_perm) {
  int nt = meta[17];
  int bt = blockIdx.y;
  if (bt >= nt) return;
  int e = meta[18 + bt];
  int row0 = meta[90 + bt];
  int rows_end = meta[e + 1];
  int n0 = blockIdx.x * 128;

  __shared__ __align__(16) bfbits As[128 * 32];
  __shared__ __align__(16) bfbits Bs[128 * 32];

  int tid = threadIdx.x, lane = tid & 63, wv = tid >> 6;
  int g = (lane & 3) ^ ((lane >> 3) & 3);
  int rlo = lane >> 2;

  const bfbits* apt[2]; const bfbits* bpt[2];
  int ldsoff[2];
  for (int j = 0; j < 2; j++) {
    int s = 2 * wv + j;
    int rit = 16 * s + rlo;
    apt[j] = hb + (size_t)(row0 + rit) * H_DIM + g * 8;   // rows already sorted
    bpt[j] = w2t + ((size_t)e * D_MODEL + n0 + rit) * H_DIM + g * 8;
    ldsoff[j] = s * 512;
  }

  const f32x4 fzero = {0.f, 0.f, 0.f, 0.f};
  f32x4 acc[4][4];
  for (int i = 0; i < 4; i++)
    for (int j = 0; j < 4; j++) acc[i][j] = fzero;

  int mw = (wv & 1) * 64, nw = (wv >> 1) * 64;
  int qd = lane >> 4, lr = lane & 15;
  int slot = (qd ^ ((lr >> 1) & 3)) << 3;

  for (int kk = 0; kk < H_DIM / 32; kk++) {
    int ko = kk * 32;
    glds16(apt[0] + ko, As + ldsoff[0]);
    glds16(apt[1] + ko, As + ldsoff[1]);
    glds16(bpt[0] + ko, Bs + ldsoff[0]);
    glds16(bpt[1] + ko, Bs + ldsoff[1]);
    __syncthreads();
    bf16x8 af[4], bfr[4];
    for (int mi = 0; mi < 4; mi++)
      af[mi] = *(const bf16x8*)&As[(mw + mi * 16 + lr) * 32 + slot];
    for (int ni = 0; ni < 4; ni++)
      bfr[ni] = *(const bf16x8*)&Bs[(nw + ni * 16 + lr) * 32 + slot];
    for (int mi = 0; mi < 4; mi++)
      for (int ni = 0; ni < 4; ni++)
        acc[mi][ni] = __builtin_amdgcn_mfma_f32_16x16x32_bf16(af[mi], bfr[ni], acc[mi][ni], 0, 0, 0);
    __syncthreads();
  }

  for (int mi = 0; mi < 4; mi++) {
    int rbase = row0 + mw + mi * 16 + qd * 4;
    for (int r = 0; r < 4; r++) {
      int grow = rbase + r;
      if (grow < rows_end) {
        for (int ni = 0; ni < 4; ni++)
          out_perm[(size_t)grow * D_MODEL + n0 + nw + ni * 16 + lr] = acc[mi][ni][r];
      }
    }
  }
}

// ---- weighted combine of the two copies per token ----
__global__ void combine_kernel(const float4* __restrict__ out_perm,
                               const int* __restrict__ pos_of,
                               const float* __restrict__ ew, float4* __restrict__ out) {
  int i = blockIdx.x * 256 + threadIdx.x;  // over N_TOK * D/4
  int tok = i >> 8;                         // D/4 = 256
  int col = i & 255;
  int p0 = pos_of[2 * tok], p1 = pos_of[2 * tok + 1];
  float w0 = ew[2 * tok], w1 = ew[2 * tok + 1];
  float4 a = out_perm[(size_t)p0 * 256 + col];
  float4 b = out_perm[(size_t)p1 * 256 + col];
  float4 o;
  o.x = w0 * a.x + w1 * b.x;
  o.y = w0 * a.y + w1 * b.y;
  o.z = w0 * a.z + w1 * b.z;
  o.w = w0 * a.w + w1 * b.w;
  out[i] = o;
}

extern "C" void kernel_launch(void* const* d_in, const int* in_sizes, int n_in,
                              void* d_out, int out_size, void* d_ws, size_t ws_size,
                              hipStream_t stream) {
  const float* x  = (const float*)d_in[0];
  const float* ew = (const float*)d_in[1];
  const int* eidx = (const int*)d_in[2];
  const int* bspe = (const int*)d_in[3];
  const float* w1 = (const float*)d_in[4];
  const float* w2 = (const float*)d_in[5];
  const float* w3 = (const float*)d_in[6];
  float* out = (float*)d_out;

  char* ws = (char*)d_ws;
  const size_t MB = 1024 * 1024;
  bfbits* w1t   = (bfbits*)(ws);             // 16 MB (E,H,D)
  bfbits* w3t   = (bfbits*)(ws + 16 * MB);   // 16 MB (E,H,D)
  bfbits* w2t   = (bfbits*)(ws + 32 * MB);   // 16 MB (E,D,H)
  bfbits* xb    = (bfbits*)(ws + 48 * MB);   //  8 MB (N,D)
  bfbits* hb    = (bfbits*)(ws + 56 * MB);   // 16 MB (NK,H)
  // out_perm (32 MB fp32) aliases w1t/w3t — dead after gemm_swiglu completes
  float* out_perm = (float*)(ws);
  int* row_src  = (int*)(ws + 72 * MB);              // 32 KB
  int* pos_of   = (int*)(ws + 72 * MB + 32 * 1024);  // 32 KB
  int* meta     = (int*)(ws + 72 * MB + 64 * 1024);

  prep_kernel<<<1, 64, 0, stream>>>(bspe, meta);
  bucket_kernel<<<NK / 256, 256, 0, stream>>>(eidx, meta, row_src, pos_of);
  convx_kernel<<<(N_TOK * D_MODEL / 4) / 256, 256, 0, stream>>>((const float4*)x, (ushort4*)xb);
  wtrans_kernel<<<dim3(16, 16, 24), 256, 0, stream>>>(w1, w2, w3, w1t, w2t, w3t);
  // grid (n0, tile): 8 consecutive blocks share the A tile (L2 locality)
  gemm_swiglu_kernel<<<dim3(H_DIM / 128, MAX_TILES), 256, 0, stream>>>(
      xb, w1t, w3t, row_src, meta, hb);
  gemm_out_kernel<<<dim3(D_MODEL / 128, MAX_TILES), 256, 0, stream>>>(
      hb, w2t, meta, out_perm);
  combine_kernel<<<(N_TOK * D_MODEL / 4) / 256, 256, 0, stream>>>(
      (const float4*)out_perm, pos_of, ew, (float4*)out);
}

// Round 3
// 283.132 us; speedup vs baseline: 1.1948x; 1.0786x over previous
//
#include <hip/hip_runtime.h>
#include <hip/hip_bf16.h>
#include <stdint.h>

// Problem constants: N=4096, K=2, E=8, D=1024, H=1024
#define N_TOK   4096
#define TOPK    2
#define N_EXP   8
#define D_MODEL 1024
#define H_DIM   1024
#define NK      (N_TOK * TOPK)   // 8192 token-copies
#define MAX_TILES 72             // sum over experts of ceil(gs/128) <= 64+7

typedef __attribute__((ext_vector_type(8))) short bf16x8;  // 8 bf16 (4 VGPRs)
typedef __attribute__((ext_vector_type(4))) float f32x4;   // MFMA accumulator
typedef unsigned short bfbits;

__device__ inline bfbits f2bf_bits(float f) {
  union { float f; unsigned int u; } v; v.f = f;
  unsigned int r = v.u + 0x7FFFu + ((v.u >> 16) & 1u);  // RNE
  return (bfbits)(r >> 16);
}

// async global->LDS, 16B/lane; LDS dest = wave-uniform base + lane*16
__device__ inline void glds16(const bfbits* g, bfbits* l) {
  __builtin_amdgcn_global_load_lds(
      (const __attribute__((address_space(1))) void*)g,
      (__attribute__((address_space(3))) void*)l, 16, 0, 0);
}

// meta: [0..8] offs (excl scan), [17] ntiles, [18..89] tile_expert, [90..161] tile_row0
__global__ void prep_bucket_kernel(const int* __restrict__ bspe, const int* __restrict__ eidx,
                                   int* __restrict__ meta, int* __restrict__ row_src,
                                   int* __restrict__ pos_of) {
  __shared__ int sm[162];
  __shared__ int scnt[N_EXP];
  int t = threadIdx.x;
  if (t == 0) {
    int acc = 0, nt = 0;
    for (int e = 0; e < N_EXP; e++) {
      sm[e] = acc;
      sm[9 + e] = 0;
      int g = bspe[e];
      for (int tt = 0; tt * 128 < g; tt++) {
        sm[18 + nt] = e;
        sm[90 + nt] = acc + tt * 128;
        nt++;
      }
      acc += g;
    }
    sm[8] = acc;
    sm[17] = nt;
    for (int i = nt; i < MAX_TILES; i++) { sm[18 + i] = 0; sm[90 + i] = 0; }
  }
  if (t < N_EXP) scnt[t] = 0;
  __syncthreads();
  for (int i = t; i < NK; i += 256) {
    int e = eidx[i];
    int p = sm[e] + atomicAdd(&scnt[e], 1);
    row_src[p] = i;
    pos_of[i] = p;
  }
  if (t < 162) meta[t] = sm[t];
}

__global__ void convx_kernel(const float4* __restrict__ x, ushort4* __restrict__ xb) {
  int i = blockIdx.x * 256 + threadIdx.x;
  float4 v = x[i];
  ushort4 o;
  o.x = f2bf_bits(v.x); o.y = f2bf_bits(v.y);
  o.z = f2bf_bits(v.z); o.w = f2bf_bits(v.w);
  xb[i] = o;
}

// Transpose+convert 24 1024x1024 fp32 matrices -> bf16 transposed.
__global__ void wtrans_kernel(const float* __restrict__ w1, const float* __restrict__ w2,
                              const float* __restrict__ w3,
                              bfbits* __restrict__ w1t, bfbits* __restrict__ w2t,
                              bfbits* __restrict__ w3t) {
  int z = blockIdx.z;
  const size_t MAT = (size_t)1024 * 1024;
  const float* src; bfbits* dst;
  if (z < 8)       { src = w1 + (size_t)z * MAT;        dst = w1t + (size_t)z * MAT; }
  else if (z < 16) { src = w3 + (size_t)(z - 8) * MAT;  dst = w3t + (size_t)(z - 8) * MAT; }
  else             { src = w2 + (size_t)(z - 16) * MAT; dst = w2t + (size_t)(z - 16) * MAT; }
  __shared__ bfbits tl[64][65];   // odd stride -> 2-way banks (free)
  int tid = threadIdx.x;
  int r0 = blockIdx.y * 64, c0 = blockIdx.x * 64;
  for (int it = 0; it < 4; it++) {
    int r = (tid >> 4) + it * 16;
    int c = (tid & 15) * 4;
    float4 v = *(const float4*)&src[(size_t)(r0 + r) * 1024 + c0 + c];
    tl[r][c + 0] = f2bf_bits(v.x); tl[r][c + 1] = f2bf_bits(v.y);
    tl[r][c + 2] = f2bf_bits(v.z); tl[r][c + 3] = f2bf_bits(v.w);
  }
  __syncthreads();
  for (int it = 0; it < 4; it++) {
    int o = (tid >> 4) + it * 16;   // output row (= source col) 0..63
    int r4 = (tid & 15) * 4;        // source-row quad
    ushort4 v;
    v.x = tl[r4 + 0][o]; v.y = tl[r4 + 1][o];
    v.z = tl[r4 + 2][o]; v.w = tl[r4 + 3][o];
    *(ushort4*)&dst[(size_t)(c0 + o) * 1024 + r0 + r4] = v;
  }
}

// ---- grouped GEMM 1: h = silu(x@w1) * (x@w3), bf16 out (NK,H) ----
// 128x64xBK32 tile, 4 waves of 64x32, dual acc (64 AGPR). glds staging,
// XOR segment swizzle (verified 0 bank conflicts in R2).
__global__ __launch_bounds__(256, 3) void gemm_swiglu_kernel(
    const bfbits* __restrict__ xb, const bfbits* __restrict__ w1t,
    const bfbits* __restrict__ w3t, const int* __restrict__ row_src,
    const int* __restrict__ meta, bfbits* __restrict__ hb) {
  int nt = meta[17];
  int bt = blockIdx.y;
  if (bt >= nt) return;
  int e = meta[18 + bt];
  int row0 = meta[90 + bt];
  int rows_end = meta[e + 1];
  int n0 = blockIdx.x * 64;

  __shared__ __align__(16) bfbits As[128 * 32];   // 8 KB
  __shared__ __align__(16) bfbits B1s[64 * 32];   // 4 KB
  __shared__ __align__(16) bfbits B3s[64 * 32];   // 4 KB

  int tid = threadIdx.x, lane = tid & 63, wv = tid >> 6;
  int g = (lane & 3) ^ ((lane >> 3) & 3);  // swizzled global 16B segment
  int rlo = lane >> 2;                      // row within a 16-row segment

  // 16 staging segments: [0..7]=A rows, [8..11]=B1 rows, [12..15]=B3 rows
  const bfbits* gp[4]; bfbits* lp[4];
  for (int j = 0; j < 4; j++) {
    int s = wv * 4 + j;
    if (s < 8) {
      int gr = row0 + s * 16 + rlo;
      int tok = row_src[(gr < rows_end) ? gr : row0] >> 1;  // TOPK=2
      gp[j] = xb + (size_t)tok * D_MODEL + g * 8;
      lp[j] = As + s * 512;
    } else if (s < 12) {
      int b = s - 8;
      gp[j] = w1t + ((size_t)e * H_DIM + n0 + b * 16 + rlo) * D_MODEL + g * 8;
      lp[j] = B1s + b * 512;
    } else {
      int b = s - 12;
      gp[j] = w3t + ((size_t)e * H_DIM + n0 + b * 16 + rlo) * D_MODEL + g * 8;
      lp[j] = B3s + b * 512;
    }
  }

  const f32x4 fzero = {0.f, 0.f, 0.f, 0.f};
  f32x4 accg[4][2], accu[4][2];
  for (int i = 0; i < 4; i++)
    for (int j = 0; j < 2; j++) { accg[i][j] = fzero; accu[i][j] = fzero; }

  int mw = (wv & 1) * 64, nwv = (wv >> 1) * 32;
  int qd = lane >> 4, lr = lane & 15;
  int slot = (qd ^ ((lr >> 1) & 3)) << 3;  // element offset of my 16B slot

  for (int kk = 0; kk < D_MODEL / 32; kk++) {
    int ko = kk * 32;
    glds16(gp[0] + ko, lp[0]);
    glds16(gp[1] + ko, lp[1]);
    glds16(gp[2] + ko, lp[2]);
    glds16(gp[3] + ko, lp[3]);
    __syncthreads();
    bf16x8 af[4], b1f[2], b3f[2];
    for (int mi = 0; mi < 4; mi++)
      af[mi] = *(const bf16x8*)&As[(mw + mi * 16 + lr) * 32 + slot];
    for (int ni = 0; ni < 2; ni++) {
      b1f[ni] = *(const bf16x8*)&B1s[(nwv + ni * 16 + lr) * 32 + slot];
      b3f[ni] = *(const bf16x8*)&B3s[(nwv + ni * 16 + lr) * 32 + slot];
    }
    for (int mi = 0; mi < 4; mi++)
      for (int ni = 0; ni < 2; ni++) {
        accg[mi][ni] = __builtin_amdgcn_mfma_f32_16x16x32_bf16(af[mi], b1f[ni], accg[mi][ni], 0, 0, 0);
        accu[mi][ni] = __builtin_amdgcn_mfma_f32_16x16x32_bf16(af[mi], b3f[ni], accu[mi][ni], 0, 0, 0);
      }
    __syncthreads();
  }

  // C/D layout: row=(lane>>4)*4+reg, col=lane&15
  for (int mi = 0; mi < 4; mi++) {
    int rbase = row0 + mw + mi * 16 + qd * 4;
    for (int r = 0; r < 4; r++) {
      int grow = rbase + r;
      if (grow < rows_end) {
        for (int ni = 0; ni < 2; ni++) {
          float gg = accg[mi][ni][r], u = accu[mi][ni][r];
          float h = gg / (1.f + __expf(-gg)) * u;  // silu(g)*u
          hb[(size_t)grow * H_DIM + n0 + nwv + ni * 16 + lr] = f2bf_bits(h);
        }
      }
    }
  }
}

// ---- grouped GEMM 2: out_perm = h @ w2 (fp32, no atomics) ----
// 128x64xBK32 tile, 4 waves of 64x32, single acc (32 AGPR).
__global__ __launch_bounds__(256, 4) void gemm_out_kernel(
    const bfbits* __restrict__ hb, const bfbits* __restrict__ w2t,
    const int* __restrict__ meta, float* __restrict__ out_perm) {
  int nt = meta[17];
  int bt = blockIdx.y;
  if (bt >= nt) return;
  int e = meta[18 + bt];
  int row0 = meta[90 + bt];
  int rows_end = meta[e + 1];
  int n0 = blockIdx.x * 64;

  __shared__ __align__(16) bfbits As[128 * 32];   // 8 KB
  __shared__ __align__(16) bfbits Bs[64 * 32];    // 4 KB

  int tid = threadIdx.x, lane = tid & 63, wv = tid >> 6;
  int g = (lane & 3) ^ ((lane >> 3) & 3);
  int rlo = lane >> 2;

  // 12 staging segments: [0..7]=A rows, [8..11]=B rows; 3 per wave
  const bfbits* gp[3]; bfbits* lp[3];
  for (int j = 0; j < 3; j++) {
    int s = wv * 3 + j;
    if (s < 8) {
      int gr = row0 + s * 16 + rlo;
      int sr = (gr < rows_end) ? gr : row0;
      gp[j] = hb + (size_t)sr * H_DIM + g * 8;
      lp[j] = As + s * 512;
    } else {
      int b = s - 8;
      gp[j] = w2t + ((size_t)e * D_MODEL + n0 + b * 16 + rlo) * H_DIM + g * 8;
      lp[j] = Bs + b * 512;
    }
  }

  const f32x4 fzero = {0.f, 0.f, 0.f, 0.f};
  f32x4 acc[4][2];
  for (int i = 0; i < 4; i++)
    for (int j = 0; j < 2; j++) acc[i][j] = fzero;

  int mw = (wv & 1) * 64, nwv = (wv >> 1) * 32;
  int qd = lane >> 4, lr = lane & 15;
  int slot = (qd ^ ((lr >> 1) & 3)) << 3;

  for (int kk = 0; kk < H_DIM / 32; kk++) {
    int ko = kk * 32;
    glds16(gp[0] + ko, lp[0]);
    glds16(gp[1] + ko, lp[1]);
    glds16(gp[2] + ko, lp[2]);
    __syncthreads();
    bf16x8 af[4], bfr[2];
    for (int mi = 0; mi < 4; mi++)
      af[mi] = *(const bf16x8*)&As[(mw + mi * 16 + lr) * 32 + slot];
    for (int ni = 0; ni < 2; ni++)
      bfr[ni] = *(const bf16x8*)&Bs[(nwv + ni * 16 + lr) * 32 + slot];
    for (int mi = 0; mi < 4; mi++)
      for (int ni = 0; ni < 2; ni++)
        acc[mi][ni] = __builtin_amdgcn_mfma_f32_16x16x32_bf16(af[mi], bfr[ni], acc[mi][ni], 0, 0, 0);
    __syncthreads();
  }

  for (int mi = 0; mi < 4; mi++) {
    int rbase = row0 + mw + mi * 16 + qd * 4;
    for (int r = 0; r < 4; r++) {
      int grow = rbase + r;
      if (grow < rows_end) {
        for (int ni = 0; ni < 2; ni++)
          out_perm[(size_t)grow * D_MODEL + n0 + nwv + ni * 16 + lr] = acc[mi][ni][r];
      }
    }
  }
}

// ---- weighted combine of the two copies per token ----
__global__ void combine_kernel(const float4* __restrict__ out_perm,
                               const int* __restrict__ pos_of,
                               const float* __restrict__ ew, float4* __restrict__ out) {
  int i = blockIdx.x * 256 + threadIdx.x;  // over N_TOK * D/4
  int tok = i >> 8;                         // D/4 = 256
  int col = i & 255;
  int p0 = pos_of[2 * tok], p1 = pos_of[2 * tok + 1];
  float w0 = ew[2 * tok], w1 = ew[2 * tok + 1];
  float4 a = out_perm[(size_t)p0 * 256 + col];
  float4 b = out_perm[(size_t)p1 * 256 + col];
  float4 o;
  o.x = w0 * a.x + w1 * b.x;
  o.y = w0 * a.y + w1 * b.y;
  o.z = w0 * a.z + w1 * b.z;
  o.w = w0 * a.w + w1 * b.w;
  out[i] = o;
}

extern "C" void kernel_launch(void* const* d_in, const int* in_sizes, int n_in,
                              void* d_out, int out_size, void* d_ws, size_t ws_size,
                              hipStream_t stream) {
  const float* x  = (const float*)d_in[0];
  const float* ew = (const float*)d_in[1];
  const int* eidx = (const int*)d_in[2];
  const int* bspe = (const int*)d_in[3];
  const float* w1 = (const float*)d_in[4];
  const float* w2 = (const float*)d_in[5];
  const float* w3 = (const float*)d_in[6];
  float* out = (float*)d_out;

  char* ws = (char*)d_ws;
  const size_t MB = 1024 * 1024;
  bfbits* w1t   = (bfbits*)(ws);             // 16 MB (E,H,D)
  bfbits* w3t   = (bfbits*)(ws + 16 * MB);   // 16 MB (E,H,D)
  bfbits* w2t   = (bfbits*)(ws + 32 * MB);   // 16 MB (E,D,H)
  bfbits* xb    = (bfbits*)(ws + 48 * MB);   //  8 MB (N,D)
  bfbits* hb    = (bfbits*)(ws + 56 * MB);   // 16 MB (NK,H)
  // out_perm (32 MB fp32) aliases w1t/w3t — dead after gemm_swiglu completes
  float* out_perm = (float*)(ws);
  int* row_src  = (int*)(ws + 72 * MB);              // 32 KB
  int* pos_of   = (int*)(ws + 72 * MB + 32 * 1024);  // 32 KB
  int* meta     = (int*)(ws + 72 * MB + 64 * 1024);

  prep_bucket_kernel<<<1, 256, 0, stream>>>(bspe, eidx, meta, row_src, pos_of);
  convx_kernel<<<(N_TOK * D_MODEL / 4) / 256, 256, 0, stream>>>((const float4*)x, (ushort4*)xb);
  wtrans_kernel<<<dim3(16, 16, 24), 256, 0, stream>>>(w1, w2, w3, w1t, w2t, w3t);
  gemm_swiglu_kernel<<<dim3(H_DIM / 64, MAX_TILES), 256, 0, stream>>>(
      xb, w1t, w3t, row_src, meta, hb);
  gemm_out_kernel<<<dim3(D_MODEL / 64, MAX_TILES), 256, 0, stream>>>(
      hb, w2t, meta, out_perm);
  combine_kernel<<<(N_TOK * D_MODEL / 4) / 256, 256, 0, stream>>>(
      (const float4*)out_perm, pos_of, ew, (float4*)out);
}

// Round 4
// 248.617 us; speedup vs baseline: 1.3607x; 1.1388x over previous
//
#include <hip/hip_runtime.h>
#include <hip/hip_bf16.h>
#include <stdint.h>

// Problem constants: N=4096, K=2, E=8, D=1024, H=1024
#define N_TOK   4096
#define TOPK    2
#define N_EXP   8
#define D_MODEL 1024
#define H_DIM   1024
#define NK      (N_TOK * TOPK)   // 8192 token-copies
#define MAX_TILES 72             // sum over experts of ceil(gs/128) <= 64+7

typedef __attribute__((ext_vector_type(8))) short bf16x8;  // 8 bf16 (4 VGPRs)
typedef __attribute__((ext_vector_type(4))) float f32x4;   // MFMA accumulator
typedef unsigned short bfbits;

__device__ inline bfbits f2bf_bits(float f) {
  union { float f; unsigned int u; } v; v.f = f;
  unsigned int r = v.u + 0x7FFFu + ((v.u >> 16) & 1u);  // RNE
  return (bfbits)(r >> 16);
}
__device__ inline float bf2f(unsigned short u) {
  union { unsigned int u; float f; } v; v.u = ((unsigned int)u) << 16;
  return v.f;
}

// async global->LDS, 16B/lane; LDS dest = wave-uniform base + lane*16
__device__ inline void glds16(const bfbits* g, bfbits* l) {
  __builtin_amdgcn_global_load_lds(
      (const __attribute__((address_space(1))) void*)g,
      (__attribute__((address_space(3))) void*)l, 16, 0, 0);
}

// ---- fused pre-pass ----
// z < 24 : transpose+convert weight matrix z (w1:0-7, w3:8-15, w2:16-23)
// 24<=z<40: convert x -> bf16 (chunked)
// z == 40 : (block 0,0 only) prep meta + bucket sort
// meta: [0..8] offs (excl scan), [17] ntiles, [18..89] tile_expert, [90..161] tile_row0
__global__ void prepass_kernel(const float* __restrict__ x, const int* __restrict__ eidx,
                               const int* __restrict__ bspe,
                               const float* __restrict__ w1, const float* __restrict__ w2,
                               const float* __restrict__ w3,
                               bfbits* __restrict__ w1t, bfbits* __restrict__ w2t,
                               bfbits* __restrict__ w3t, bfbits* __restrict__ xb,
                               int* __restrict__ meta, int* __restrict__ row_src,
                               int* __restrict__ pos_of) {
  int z = blockIdx.z;
  int tid = threadIdx.x;
  if (z < 24) {
    const size_t MAT = (size_t)1024 * 1024;
    const float* src; bfbits* dst;
    if (z < 8)       { src = w1 + (size_t)z * MAT;        dst = w1t + (size_t)z * MAT; }
    else if (z < 16) { src = w3 + (size_t)(z - 8) * MAT;  dst = w3t + (size_t)(z - 8) * MAT; }
    else             { src = w2 + (size_t)(z - 16) * MAT; dst = w2t + (size_t)(z - 16) * MAT; }
    __shared__ bfbits tl[64][65];   // odd stride -> 2-way banks (free)
    int r0 = blockIdx.y * 64, c0 = blockIdx.x * 64;
    for (int it = 0; it < 4; it++) {
      int r = (tid >> 4) + it * 16;
      int c = (tid & 15) * 4;
      float4 v = *(const float4*)&src[(size_t)(r0 + r) * 1024 + c0 + c];
      tl[r][c + 0] = f2bf_bits(v.x); tl[r][c + 1] = f2bf_bits(v.y);
      tl[r][c + 2] = f2bf_bits(v.z); tl[r][c + 3] = f2bf_bits(v.w);
    }
    __syncthreads();
    for (int it = 0; it < 4; it++) {
      int o = (tid >> 4) + it * 16;   // output row (= source col)
      int r4 = (tid & 15) * 4;        // source-row quad
      ushort4 v;
      v.x = tl[r4 + 0][o]; v.y = tl[r4 + 1][o];
      v.z = tl[r4 + 2][o]; v.w = tl[r4 + 3][o];
      *(ushort4*)&dst[(size_t)(c0 + o) * 1024 + r0 + r4] = v;
    }
  } else if (z < 40) {
    int i = ((z - 24) * 256 + blockIdx.y * 16 + blockIdx.x) * 256 + tid;  // float4 idx
    float4 v = ((const float4*)x)[i];
    ushort4 o;
    o.x = f2bf_bits(v.x); o.y = f2bf_bits(v.y);
    o.z = f2bf_bits(v.z); o.w = f2bf_bits(v.w);
    ((ushort4*)xb)[i] = o;
  } else {
    if (blockIdx.x != 0 || blockIdx.y != 0) return;
    __shared__ int sm[162];
    __shared__ int scnt[N_EXP];
    if (tid == 0) {
      int acc = 0, nt = 0;
      for (int e = 0; e < N_EXP; e++) {
        sm[e] = acc;
        int g = bspe[e];
        for (int tt = 0; tt * 128 < g; tt++) {
          sm[18 + nt] = e;
          sm[90 + nt] = acc + tt * 128;
          nt++;
        }
        acc += g;
      }
      sm[8] = acc;
      sm[17] = nt;
      for (int i = nt; i < MAX_TILES; i++) { sm[18 + i] = 0; sm[90 + i] = 0; }
    }
    if (tid < N_EXP) scnt[tid] = 0;
    __syncthreads();
    for (int i = tid; i < NK; i += 256) {
      int e = eidx[i];
      int p = sm[e] + atomicAdd(&scnt[e], 1);
      row_src[p] = i;
      pos_of[i] = p;
    }
    if (tid < 162) meta[tid] = sm[tid];
  }
}

// ---- grouped GEMM 1: h = silu(x@w1) * (x@w3), bf16 out (NK,H) ----
// 128x64 tile, BK=64 (16 K-iters -> half the barrier drains of BK=32).
// 4 waves of 64x32, dual acc (64 AGPR). glds staging, 8-slot XOR swizzle.
__global__ __launch_bounds__(256, 3) void gemm_swiglu_kernel(
    const bfbits* __restrict__ xb, const bfbits* __restrict__ w1t,
    const bfbits* __restrict__ w3t, const int* __restrict__ row_src,
    const int* __restrict__ meta, bfbits* __restrict__ hb) {
  int nt = meta[17];
  int bt = blockIdx.y;
  if (bt >= nt) return;
  int e = meta[18 + bt];
  int row0 = meta[90 + bt];
  int rows_end = meta[e + 1];
  int n0 = blockIdx.x * 64;

  __shared__ __align__(16) bfbits As[128 * 64];   // 16 KB
  __shared__ __align__(16) bfbits B1s[64 * 64];   //  8 KB
  __shared__ __align__(16) bfbits B3s[64 * 64];   //  8 KB

  int tid = threadIdx.x, lane = tid & 63, wv = tid >> 6;
  int r8 = lane >> 3, jl = lane & 7;
  int jg = jl ^ r8;   // swizzled global 16B chunk for this lane

  // 32 staging segments of 8 rows each: [0..15]=A, [16..23]=B1, [24..31]=B3
  const bfbits* gp[8]; bfbits* lp[8];
  for (int j = 0; j < 8; j++) {
    int s = wv * 8 + j;
    if (s < 16) {
      int tok = row_src[row0 + s * 8 + r8] >> 1;  // TOPK=2; rows>=rows_end read valid junk, discarded
      gp[j] = xb + (size_t)tok * D_MODEL + jg * 8;
      lp[j] = As + s * 512;
    } else if (s < 24) {
      int b = s - 16;
      gp[j] = w1t + ((size_t)e * H_DIM + n0 + b * 8 + r8) * D_MODEL + jg * 8;
      lp[j] = B1s + b * 512;
    } else {
      int b = s - 24;
      gp[j] = w3t + ((size_t)e * H_DIM + n0 + b * 8 + r8) * D_MODEL + jg * 8;
      lp[j] = B3s + b * 512;
    }
  }

  const f32x4 fzero = {0.f, 0.f, 0.f, 0.f};
  f32x4 accg[4][2], accu[4][2];
  for (int i = 0; i < 4; i++)
    for (int j = 0; j < 2; j++) { accg[i][j] = fzero; accu[i][j] = fzero; }

  int mw = (wv & 1) * 64, nwv = (wv >> 1) * 32;
  int qd = lane >> 4, lr = lane & 15, lr7 = lr & 7;

  for (int kk = 0; kk < D_MODEL / 64; kk++) {
    int ko = kk * 64;
    for (int j = 0; j < 8; j++) glds16(gp[j] + ko, lp[j]);
    __syncthreads();
    for (int ks = 0; ks < 2; ks++) {
      int sb = ((ks * 4 + qd) ^ lr7) << 3;  // swizzled 16B slot in 64-el row
      bf16x8 af[4], b1f[2], b3f[2];
      for (int mi = 0; mi < 4; mi++)
        af[mi] = *(const bf16x8*)&As[(mw + mi * 16 + lr) * 64 + sb];
      for (int ni = 0; ni < 2; ni++) {
        b1f[ni] = *(const bf16x8*)&B1s[(nwv + ni * 16 + lr) * 64 + sb];
        b3f[ni] = *(const bf16x8*)&B3s[(nwv + ni * 16 + lr) * 64 + sb];
      }
      for (int mi = 0; mi < 4; mi++)
        for (int ni = 0; ni < 2; ni++) {
          accg[mi][ni] = __builtin_amdgcn_mfma_f32_16x16x32_bf16(af[mi], b1f[ni], accg[mi][ni], 0, 0, 0);
          accu[mi][ni] = __builtin_amdgcn_mfma_f32_16x16x32_bf16(af[mi], b3f[ni], accu[mi][ni], 0, 0, 0);
        }
    }
    __syncthreads();
  }

  // C/D layout: row=(lane>>4)*4+reg, col=lane&15
  for (int mi = 0; mi < 4; mi++) {
    int rbase = row0 + mw + mi * 16 + qd * 4;
    for (int r = 0; r < 4; r++) {
      int grow = rbase + r;
      if (grow < rows_end) {
        for (int ni = 0; ni < 2; ni++) {
          float gg = accg[mi][ni][r], u = accu[mi][ni][r];
          float h = gg / (1.f + __expf(-gg)) * u;  // silu(g)*u
          hb[(size_t)grow * H_DIM + n0 + nwv + ni * 16 + lr] = f2bf_bits(h);
        }
      }
    }
  }
}

// ---- grouped GEMM 2: out_perm(bf16) = h @ w2 ----
// 128x64 tile, BK=64, 4 waves of 64x32, single acc (32 AGPR), 4 blocks/CU.
__global__ __launch_bounds__(256, 4) void gemm_out_kernel(
    const bfbits* __restrict__ hb, const bfbits* __restrict__ w2t,
    const int* __restrict__ meta, bfbits* __restrict__ out_perm) {
  int nt = meta[17];
  int bt = blockIdx.y;
  if (bt >= nt) return;
  int e = meta[18 + bt];
  int row0 = meta[90 + bt];
  int rows_end = meta[e + 1];
  int n0 = blockIdx.x * 64;

  __shared__ __align__(16) bfbits As[128 * 64];   // 16 KB
  __shared__ __align__(16) bfbits Bs[64 * 64];    //  8 KB

  int tid = threadIdx.x, lane = tid & 63, wv = tid >> 6;
  int r8 = lane >> 3, jl = lane & 7;
  int jg = jl ^ r8;

  // 24 staging segments: [0..15]=A rows (hb, pre-sorted), [16..23]=B rows
  const bfbits* gp[6]; bfbits* lp[6];
  for (int j = 0; j < 6; j++) {
    int s = wv * 6 + j;
    if (s < 16) {
      gp[j] = hb + (size_t)(row0 + s * 8 + r8) * H_DIM + jg * 8;
      lp[j] = As + s * 512;
    } else {
      int b = s - 16;
      gp[j] = w2t + ((size_t)e * D_MODEL + n0 + b * 8 + r8) * H_DIM + jg * 8;
      lp[j] = Bs + b * 512;
    }
  }

  const f32x4 fzero = {0.f, 0.f, 0.f, 0.f};
  f32x4 acc[4][2];
  for (int i = 0; i < 4; i++)
    for (int j = 0; j < 2; j++) acc[i][j] = fzero;

  int mw = (wv & 1) * 64, nwv = (wv >> 1) * 32;
  int qd = lane >> 4, lr = lane & 15, lr7 = lr & 7;

  for (int kk = 0; kk < H_DIM / 64; kk++) {
    int ko = kk * 64;
    for (int j = 0; j < 6; j++) glds16(gp[j] + ko, lp[j]);
    __syncthreads();
    for (int ks = 0; ks < 2; ks++) {
      int sb = ((ks * 4 + qd) ^ lr7) << 3;
      bf16x8 af[4], bfr[2];
      for (int mi = 0; mi < 4; mi++)
        af[mi] = *(const bf16x8*)&As[(mw + mi * 16 + lr) * 64 + sb];
      for (int ni = 0; ni < 2; ni++)
        bfr[ni] = *(const bf16x8*)&Bs[(nwv + ni * 16 + lr) * 64 + sb];
      for (int mi = 0; mi < 4; mi++)
        for (int ni = 0; ni < 2; ni++)
          acc[mi][ni] = __builtin_amdgcn_mfma_f32_16x16x32_bf16(af[mi], bfr[ni], acc[mi][ni], 0, 0, 0);
    }
    __syncthreads();
  }

  for (int mi = 0; mi < 4; mi++) {
    int rbase = row0 + mw + mi * 16 + qd * 4;
    for (int r = 0; r < 4; r++) {
      int grow = rbase + r;
      if (grow < rows_end) {
        for (int ni = 0; ni < 2; ni++)
          out_perm[(size_t)grow * D_MODEL + n0 + nwv + ni * 16 + lr] = f2bf_bits(acc[mi][ni][r]);
      }
    }
  }
}

// ---- weighted combine of the two copies per token (bf16 in, fp32 out) ----
__global__ void combine_kernel(const ushort4* __restrict__ out_perm,
                               const int* __restrict__ pos_of,
                               const float* __restrict__ ew, float4* __restrict__ out) {
  int i = blockIdx.x * 256 + threadIdx.x;  // over N_TOK * D/4
  int tok = i >> 8;                         // D/4 = 256
  int col = i & 255;
  int p0 = pos_of[2 * tok], p1 = pos_of[2 * tok + 1];
  float w0 = ew[2 * tok], w1 = ew[2 * tok + 1];
  ushort4 a = out_perm[(size_t)p0 * 256 + col];
  ushort4 b = out_perm[(size_t)p1 * 256 + col];
  float4 o;
  o.x = w0 * bf2f(a.x) + w1 * bf2f(b.x);
  o.y = w0 * bf2f(a.y) + w1 * bf2f(b.y);
  o.z = w0 * bf2f(a.z) + w1 * bf2f(b.z);
  o.w = w0 * bf2f(a.w) + w1 * bf2f(b.w);
  out[i] = o;
}

extern "C" void kernel_launch(void* const* d_in, const int* in_sizes, int n_in,
                              void* d_out, int out_size, void* d_ws, size_t ws_size,
                              hipStream_t stream) {
  const float* x  = (const float*)d_in[0];
  const float* ew = (const float*)d_in[1];
  const int* eidx = (const int*)d_in[2];
  const int* bspe = (const int*)d_in[3];
  const float* w1 = (const float*)d_in[4];
  const float* w2 = (const float*)d_in[5];
  const float* w3 = (const float*)d_in[6];
  float* out = (float*)d_out;

  char* ws = (char*)d_ws;
  const size_t MB = 1024 * 1024;
  bfbits* w1t   = (bfbits*)(ws);             // 16 MB (E,H,D)
  bfbits* w3t   = (bfbits*)(ws + 16 * MB);   // 16 MB (E,H,D)
  bfbits* w2t   = (bfbits*)(ws + 32 * MB);   // 16 MB (E,D,H)
  bfbits* xb    = (bfbits*)(ws + 48 * MB);   //  8 MB (N,D)
  bfbits* hb    = (bfbits*)(ws + 56 * MB);   // 16 MB (NK,H)
  // out_perm (16 MB bf16) aliases w1t — dead after gemm_swiglu completes
  bfbits* out_perm = (bfbits*)(ws);
  int* row_src  = (int*)(ws + 72 * MB);              // 32 KB
  int* pos_of   = (int*)(ws + 72 * MB + 32 * 1024);  // 32 KB
  int* meta     = (int*)(ws + 72 * MB + 64 * 1024);

  prepass_kernel<<<dim3(16, 16, 41), 256, 0, stream>>>(
      x, eidx, bspe, w1, w2, w3, w1t, w2t, w3t, xb, meta, row_src, pos_of);
  gemm_swiglu_kernel<<<dim3(H_DIM / 64, MAX_TILES), 256, 0, stream>>>(
      xb, w1t, w3t, row_src, meta, hb);
  gemm_out_kernel<<<dim3(D_MODEL / 64, MAX_TILES), 256, 0, stream>>>(
      hb, w2t, meta, out_perm);
  combine_kernel<<<(N_TOK * D_MODEL / 4) / 256, 256, 0, stream>>>(
      (const ushort4*)out_perm, pos_of, ew, (float4*)out);
}